// Round 9
// baseline (772.833 us; speedup 1.0000x reference)
//
#include <hip/hip_runtime.h>

#define NN 100000
#define NE 1600000
#define NG 2048
#define IN_DIM 32
#define PEP_DIM 768
#define H 64
#define BN_EPS 1e-5f
#define SCAN_BLK 1024
#define NB ((NN + SCAN_BLK - 1) / SCAN_BLK)   // 98 blocks

typedef unsigned int uint;
typedef unsigned short ushort;

__device__ __forceinline__ float bf2f(uint u) {
    return __uint_as_float((u & 0xFFFFu) << 16);
}
__device__ __forceinline__ uint f2bf(float x) {
    uint b = __float_as_uint(x);
    return (b + 0x7FFFu + ((b >> 16) & 1u)) >> 16;   // RNE
}

// ---------------- degree count: deg[dst]++ ----------------
__global__ void k_degree(const int* __restrict__ ei, int* __restrict__ deg) {
    int e = blockIdx.x * 256 + threadIdx.x;
    if (e < NE) atomicAdd(&deg[ei[NE + e]], 1);
}

// ---------------- scan stage 1: per-block sums ----------------
__global__ __launch_bounds__(256) void k_scan1(const int* __restrict__ deg, int* __restrict__ bsum) {
    __shared__ int red[64];
    int base = blockIdx.x * SCAN_BLK + threadIdx.x * 4;
    int s = 0;
    for (int j = 0; j < 4; j++) {
        int i = base + j;
        if (i < NN) s += deg[i];
    }
    for (int off = 32; off > 0; off >>= 1) s += __shfl_down(s, off, 64);
    int wave = threadIdx.x >> 6;
    if ((threadIdx.x & 63) == 0) red[wave] = s;
    __syncthreads();
    if (threadIdx.x == 0) bsum[blockIdx.x] = red[0] + red[1] + red[2] + red[3];
}

// ---------------- scan stage 2 ----------------
__global__ void k_scan2(int* __restrict__ bsum, int* __restrict__ row_start) {
    if (threadIdx.x == 0) {
        int run = 0;
        for (int b = 0; b < NB; b++) { int t = bsum[b]; bsum[b] = run; run += t; }
        row_start[NN] = NE;
    }
}

// ---------------- scan stage 3 (fills row_start and cursor) ----------------
__global__ __launch_bounds__(256) void k_scan3(const int* __restrict__ deg, const int* __restrict__ bsum,
                                               int* __restrict__ row_start, int* __restrict__ cursor) {
    __shared__ int s[256];
    int base = blockIdx.x * SCAN_BLK + threadIdx.x * 4;
    int v[4];
    int tot = 0;
    for (int j = 0; j < 4; j++) {
        int i = base + j;
        v[j] = (i < NN) ? deg[i] : 0;
        tot += v[j];
    }
    s[threadIdx.x] = tot;
    __syncthreads();
    for (int off = 1; off < 256; off <<= 1) {
        int x = (threadIdx.x >= off) ? s[threadIdx.x - off] : 0;
        __syncthreads();
        s[threadIdx.x] += x;
        __syncthreads();
    }
    int excl = s[threadIdx.x] - tot + bsum[blockIdx.x];
    for (int j = 0; j < 4; j++) {
        int i = base + j;
        if (i < NN) { row_start[i] = excl; cursor[i] = excl; excl += v[j]; }
    }
}

// ---------------- fill CSR: csr[pos] = {src, packed bf16 attrs} ----------------
__global__ void k_fill(const int* __restrict__ ei, const float* __restrict__ ea,
                       int* __restrict__ cursor, int2* __restrict__ csr) {
    int e = blockIdx.x * 256 + threadIdx.x;
    if (e >= NE) return;
    int src = ei[e];
    int dst = ei[NE + e];
    float2 a = *(const float2*)(ea + e * 2);
    int pos = atomicAdd(&cursor[dst], 1);
    int2 v;
    v.x = src;
    v.y = (int)(f2bf(a.x) | (f2bf(a.y) << 16));
    csr[pos] = v;
}

// ---------------- graph boundaries from sorted batch ----------------
__global__ void k_gstart(const int* __restrict__ batch, int* __restrict__ gstart) {
    int i = blockIdx.x * 256 + threadIdx.x;
    if (i >= NN) return;
    int b = batch[i];
    int p = (i == 0) ? -1 : batch[i - 1];
    for (int g = p + 1; g <= b; g++) gstart[g] = i;
    if (i == NN - 1) {
        for (int g = b + 1; g <= NG; g++) gstart[g] = NN;
    }
}

// ---------------- h0 = x @ in_w + in_b (bf16 out) ----------------
__global__ void k_init_h(const float* __restrict__ x, const float* __restrict__ w,
                         const float* __restrict__ b, ushort* __restrict__ h) {
    int t = blockIdx.x * 256 + threadIdx.x;
    int node = t >> 4;
    if (node >= NN) return;
    int c4 = (t & 15) * 4;
    float4 acc = *(const float4*)(b + c4);
    const float* xr = x + node * IN_DIM;
    for (int k = 0; k < IN_DIM; k++) {
        float xv = xr[k];
        float4 wv = *(const float4*)(w + k * H + c4);
        acc.x += xv * wv.x; acc.y += xv * wv.y;
        acc.z += xv * wv.z; acc.w += xv * wv.w;
    }
    uint2 o;
    o.x = f2bf(acc.x) | (f2bf(acc.y) << 16);
    o.y = f2bf(acc.z) | (f2bf(acc.w) << 16);
    *(uint2*)(h + (size_t)node * H + c4) = o;
}

// ---------------- fused GINE layer: gather + MLP + BN + relu ----------------
// one wave per node. EDGE PHASE: lane l = edge-slot (l>>3), channels
// ((l&7)*8..+7) as uint4 (16B). One gather instruction = 8 edges' lines in
// flight (r8 showed per-instruction gathers serialize at ~900cy each; MLP
// must come from within one instruction). Slot sums reduced via shfl_xor
// stride 8/16/32. No __syncthreads (wave-private LDS rows).
// __launch_bounds__(256,4): (256,8) caused scratch spill (r4-r6 anomaly).
__global__ __launch_bounds__(256, 4) void k_conv(
    const ushort* __restrict__ h_in, ushort* __restrict__ h_out,
    const int2* __restrict__ csr, const int* __restrict__ row_start,
    const float* __restrict__ ew, const float* __restrict__ eb,
    const float* __restrict__ W1, const float* __restrict__ b1,
    const float* __restrict__ W2, const float* __restrict__ b2,
    const float* __restrict__ bnw, const float* __restrict__ bnb,
    const float* __restrict__ bnm, const float* __restrict__ bnv) {
    __shared__ float zs[4][H];
    __shared__ float ts[4][H];
    int w = threadIdx.x >> 6;
    int c = threadIdx.x & 63;
    int node = blockIdx.x * 4 + w;
    int s = c >> 3;          // edge slot 0..7
    int k8 = (c & 7) * 8;    // channel base for edge phase
    // per-lane edge-MLP constants for channels k8..k8+7
    float ew0v[8], ew1v[8], ebv[8];
    #pragma unroll
    for (int i = 0; i < 8; i++) {
        ew0v[i] = ew[k8 + i];
        ew1v[i] = ew[H + k8 + i];
        ebv[i]  = eb[k8 + i];
    }
    int rs = __builtin_amdgcn_readfirstlane(row_start[node]);
    int re = __builtin_amdgcn_readfirstlane(row_start[node + 1]);
    float accv[8];
    #pragma unroll
    for (int i = 0; i < 8; i++) accv[i] = 0.f;
    for (int j = rs; j < re; j += 8) {
        int idx = j + s;
        float m = (idx < re) ? 1.f : 0.f;
        idx = min(idx, re - 1);
        int2 v = csr[idx];
        float ax = bf2f((uint)v.y);
        float ay = bf2f((uint)v.y >> 16);
        uint4 hv = *(const uint4*)(h_in + (size_t)v.x * H + k8);
        const uint* hu = (const uint*)&hv;
        #pragma unroll
        for (int i = 0; i < 4; i++) {
            uint u = hu[i];
            float elo = fmaf(ax, ew0v[2 * i], fmaf(ay, ew1v[2 * i], ebv[2 * i]));
            float ehi = fmaf(ax, ew0v[2 * i + 1], fmaf(ay, ew1v[2 * i + 1], ebv[2 * i + 1]));
            accv[2 * i]     += m * fmaxf(bf2f(u) + elo, 0.f);
            accv[2 * i + 1] += m * fmaxf(bf2f(u >> 16) + ehi, 0.f);
        }
    }
    // reduce the 8 edge slots (lanes differing in bits 3..5)
    #pragma unroll
    for (int off = 8; off < 64; off <<= 1) {
        #pragma unroll
        for (int i = 0; i < 8; i++) accv[i] += __shfl_xor(accv[i], off, 64);
    }
    // z = h_self + agg for channels k8..k8+7 (all 8 slot-replicas identical)
    uint4 sv = *(const uint4*)(h_in + (size_t)node * H + k8);
    const uint* su = (const uint*)&sv;
    if (s == 0) {
        float4 z0, z1;
        z0.x = bf2f(su[0]) + accv[0];
        z0.y = bf2f(su[0] >> 16) + accv[1];
        z0.z = bf2f(su[1]) + accv[2];
        z0.w = bf2f(su[1] >> 16) + accv[3];
        z1.x = bf2f(su[2]) + accv[4];
        z1.y = bf2f(su[2] >> 16) + accv[5];
        z1.z = bf2f(su[3]) + accv[6];
        z1.w = bf2f(su[3] >> 16) + accv[7];
        *(float4*)&zs[w][k8 + 0] = z0;
        *(float4*)&zs[w][k8 + 4] = z1;
    }
    // ---- node MLP (lane = channel c), wave-private LDS, no barrier ----
    float a1 = b1[c];
    for (int k = 0; k < H; k += 4) {
        float4 zv = *(const float4*)&zs[w][k];
        a1 = fmaf(zv.x, W1[(k + 0) * H + c], a1);
        a1 = fmaf(zv.y, W1[(k + 1) * H + c], a1);
        a1 = fmaf(zv.z, W1[(k + 2) * H + c], a1);
        a1 = fmaf(zv.w, W1[(k + 3) * H + c], a1);
    }
    ts[w][c] = fmaxf(a1, 0.f);
    float a2 = b2[c];
    for (int k = 0; k < H; k += 4) {
        float4 tv = *(const float4*)&ts[w][k];
        a2 = fmaf(tv.x, W2[(k + 0) * H + c], a2);
        a2 = fmaf(tv.y, W2[(k + 1) * H + c], a2);
        a2 = fmaf(tv.z, W2[(k + 2) * H + c], a2);
        a2 = fmaf(tv.w, W2[(k + 3) * H + c], a2);
    }
    float scale = bnw[c] * rsqrtf(bnv[c] + BN_EPS);
    float hn = fmaxf((a2 - bnm[c]) * scale + bnb[c], 0.f);
    // pack 2 channels -> 1 dword store by even lanes
    uint me = f2bf(hn);
    uint nb = __shfl_down(me, 1, 64);
    if ((c & 1) == 0) {
        *(uint*)(h_out + (size_t)node * H + c) = me | (nb << 16);
    }
}

// ---------------- fused pooling + vn MLP + h += vn (addvn fused) ----------
// one wave per graph; batch sorted so graph = contiguous node range.
__global__ __launch_bounds__(256) void k_poolvn(ushort* __restrict__ h,
                                                const int* __restrict__ gstart,
                                                float* __restrict__ pooled,
                                                const float* __restrict__ w1, const float* __restrict__ b1,
                                                const float* __restrict__ w2, const float* __restrict__ b2,
                                                float* __restrict__ vn, int do_vn) {
    __shared__ float ps[4][H];
    __shared__ float ts[4][H];
    int w = threadIdx.x >> 6, c = threadIdx.x & 63;
    int g = blockIdx.x * 4 + w;
    int s = __builtin_amdgcn_readfirstlane(gstart[g]);
    int e = __builtin_amdgcn_readfirstlane(gstart[g + 1]);
    float acc = 0.f;
    int n = s;
    for (; n + 4 <= e; n += 4) {
        float x0 = bf2f(h[(size_t)(n + 0) * H + c]);
        float x1 = bf2f(h[(size_t)(n + 1) * H + c]);
        float x2 = bf2f(h[(size_t)(n + 2) * H + c]);
        float x3 = bf2f(h[(size_t)(n + 3) * H + c]);
        acc += x0; acc += x1; acc += x2; acc += x3;
    }
    for (; n < e; n++) acc += bf2f(h[(size_t)n * H + c]);
    pooled[(size_t)g * H + c] = acc;
    if (!do_vn) return;
    ps[w][c] = acc;
    float a1 = b1[c];
    for (int k = 0; k < H; k += 4) {
        float4 pv = *(const float4*)&ps[w][k];
        a1 = fmaf(pv.x, w1[(k + 0) * H + c], a1);
        a1 = fmaf(pv.y, w1[(k + 1) * H + c], a1);
        a1 = fmaf(pv.z, w1[(k + 2) * H + c], a1);
        a1 = fmaf(pv.w, w1[(k + 3) * H + c], a1);
    }
    ts[w][c] = fmaxf(a1, 0.f);
    float a2 = b2[c];
    for (int k = 0; k < H; k += 4) {
        float4 tv = *(const float4*)&ts[w][k];
        a2 = fmaf(tv.x, w2[(k + 0) * H + c], a2);
        a2 = fmaf(tv.y, w2[(k + 1) * H + c], a2);
        a2 = fmaf(tv.z, w2[(k + 2) * H + c], a2);
        a2 = fmaf(tv.w, w2[(k + 3) * H + c], a2);
    }
    float vnew = vn[(size_t)g * H + c] + a2;
    vn[(size_t)g * H + c] = vnew;
    // ---- fused addvn: h[n] += vnew for all nodes n of graph g ----
    ps[w][c] = vnew;
    float vlo = ps[w][(c & 31) * 2 + 0];
    float vhi = ps[w][(c & 31) * 2 + 1];
    int ch2 = (c & 31) * 2;
    for (n = s; n + 2 <= e; n += 2) {
        size_t off = (size_t)(n + (c >> 5)) * H + ch2;
        uint u = *(uint*)(h + off);
        float lo = bf2f(u) + vlo;
        float hi = bf2f(u >> 16) + vhi;
        *(uint*)(h + off) = f2bf(lo) | (f2bf(hi) << 16);
    }
    if (n < e && c < 32) {   // odd tail
        size_t off = (size_t)n * H + ch2;
        uint u = *(uint*)(h + off);
        float lo = bf2f(u) + vlo;
        float hi = bf2f(u >> 16) + vhi;
        *(uint*)(h + off) = f2bf(lo) | (f2bf(hi) << 16);
    }
}

// ---------------- final: mean pool, pep MLP, classifier ----------------
__global__ __launch_bounds__(256) void k_final(const float* __restrict__ pooled,
                                               const int* __restrict__ gstart,
                                               const float* __restrict__ pep,
                                               const float* __restrict__ pw, const float* __restrict__ pb,
                                               const float* __restrict__ cw1, const float* __restrict__ cb1,
                                               const float* __restrict__ cw2, const float* __restrict__ cb2,
                                               float* __restrict__ out) {
    __shared__ float red[4][H];
    __shared__ float fused[2 * H];
    int g = blockIdx.x;
    int lane = threadIdx.x & 63;
    int part = threadIdx.x >> 6;
    const float* pr = pep + (size_t)g * PEP_DIM;
    float acc = 0.0f;
    int k0 = part * (PEP_DIM / 4);
    for (int k = k0; k < k0 + PEP_DIM / 4; k++) {
        acc += pr[k] * pw[k * H + lane];
    }
    red[part][lane] = acc;
    __syncthreads();
    if (part == 0) {
        float s = red[0][lane] + red[1][lane] + red[2][lane] + red[3][lane] + pb[lane];
        fused[H + lane] = fmaxf(s, 0.0f);
        float c = (float)(gstart[g + 1] - gstart[g]);
        float invc = 1.0f / fmaxf(c, 1.0f);
        fused[lane] = pooled[(size_t)g * H + lane] * invc;
    }
    __syncthreads();
    if (part == 0) {
        float a = cb1[lane];
        for (int k = 0; k < 2 * H; k++) a += fused[k] * cw1[k * H + lane];
        float t = fmaxf(a, 0.0f);
        float v = t * cw2[lane];
        for (int off = 32; off > 0; off >>= 1) v += __shfl_down(v, off, 64);
        if (lane == 0) out[g] = v + cb2[0];
    }
}

extern "C" void kernel_launch(void* const* d_in, const int* in_sizes, int n_in,
                              void* d_out, int out_size, void* d_ws, size_t ws_size,
                              hipStream_t stream) {
    const float* x        = (const float*)d_in[0];
    const int*   ei       = (const int*)d_in[1];
    const int*   batch    = (const int*)d_in[2];
    const float* ea       = (const float*)d_in[3];
    const float* pep      = (const float*)d_in[4];
    const float* in_w     = (const float*)d_in[5];
    const float* in_b     = (const float*)d_in[6];
    const float* e_w      = (const float*)d_in[7];
    const float* e_b      = (const float*)d_in[8];
    const float* conv_w1  = (const float*)d_in[9];
    const float* conv_b1  = (const float*)d_in[10];
    const float* conv_w2  = (const float*)d_in[11];
    const float* conv_b2  = (const float*)d_in[12];
    const float* bn_w     = (const float*)d_in[13];
    const float* bn_b     = (const float*)d_in[14];
    const float* bn_mean  = (const float*)d_in[15];
    const float* bn_var   = (const float*)d_in[16];
    const float* vn_w1    = (const float*)d_in[17];
    const float* vn_b1    = (const float*)d_in[18];
    const float* vn_w2    = (const float*)d_in[19];
    const float* vn_b2    = (const float*)d_in[20];
    const float* pep_w    = (const float*)d_in[21];
    const float* pep_b    = (const float*)d_in[22];
    const float* cls_w1   = (const float*)d_in[23];
    const float* cls_b1   = (const float*)d_in[24];
    const float* cls_w2   = (const float*)d_in[25];
    const float* cls_b2   = (const float*)d_in[26];
    float* out = (float*)d_out;

    // ---- workspace layout ----
    ushort* h_a   = (ushort*)d_ws;                    // NN*H bf16
    ushort* h_b   = h_a + (size_t)NN * H;             // NN*H bf16
    float* pooled = (float*)(h_b + (size_t)NN * H);   // NG*H
    float* vn     = pooled + (size_t)NG * H;          // NG*H
    int2*  csr    = (int2*)(vn + (size_t)NG * H);     // NE (8B each)
    int* row_start = (int*)(csr + (size_t)NE);        // NN+16
    int* cursor    = row_start + NN + 16;             // NN+16
    int* gstart    = cursor + NN + 16;                // NG+16
    int* bsum      = gstart + NG + 16;                // NB (<=128)

    // ---- build CSR (once; reused by all 3 layers) ----
    hipMemsetAsync(cursor, 0, (size_t)NN * sizeof(int), stream);
    k_degree<<<(NE + 255) / 256, 256, 0, stream>>>(ei, cursor);
    k_scan1<<<NB, 256, 0, stream>>>(cursor, bsum);
    k_scan2<<<1, 64, 0, stream>>>(bsum, row_start);
    k_scan3<<<NB, 256, 0, stream>>>(cursor, bsum, row_start, cursor);
    k_fill<<<(NE + 255) / 256, 256, 0, stream>>>(ei, ea, cursor, csr);
    k_gstart<<<(NN + 255) / 256, 256, 0, stream>>>(batch, gstart);

    // ---- init ----
    k_init_h<<<NN * 16 / 256, 256, 0, stream>>>(x, in_w, in_b, h_a);
    hipMemsetAsync(vn, 0, (size_t)NG * H * sizeof(float), stream);

    ushort* hc = h_a;
    ushort* hn = h_b;
    for (int i = 0; i < 3; i++) {
        k_conv<<<NN / 4, 256, 0, stream>>>(hc, hn, csr, row_start,
                                           e_w, e_b,
                                           conv_w1 + i * H * H, conv_b1 + i * H,
                                           conv_w2 + i * H * H, conv_b2 + i * H,
                                           bn_w + i * H, bn_b + i * H,
                                           bn_mean + i * H, bn_var + i * H);
        ushort* t = hc; hc = hn; hn = t;   // hc now holds layer output
        k_poolvn<<<NG / 4, 256, 0, stream>>>(hc, gstart, pooled,
                                             vn_w1, vn_b1, vn_w2, vn_b2, vn,
                                             (i < 2) ? 1 : 0);
    }

    k_final<<<NG, 256, 0, stream>>>(pooled, gstart, pep, pep_w, pep_b,
                                    cls_w1, cls_b1, cls_w2, cls_b2, out);
}

// Round 10
// 648.050 us; speedup vs baseline: 1.1926x; 1.1926x over previous
//
#include <hip/hip_runtime.h>

#define NN 100000
#define NE 1600000
#define NG 2048
#define IN_DIM 32
#define PEP_DIM 768
#define H 64
#define BN_EPS 1e-5f
#define SCAN_BLK 1024
#define NB ((NN + SCAN_BLK - 1) / SCAN_BLK)   // 98 blocks
#define CONV_W 16   // waves (=nodes) per k_conv block

typedef unsigned int uint;
typedef unsigned short ushort;

__device__ __forceinline__ float bf2f(uint u) {
    return __uint_as_float((u & 0xFFFFu) << 16);
}
__device__ __forceinline__ uint f2bf(float x) {
    uint b = __float_as_uint(x);
    return (b + 0x7FFFu + ((b >> 16) & 1u)) >> 16;   // RNE
}

// ---------------- degree count: deg[dst]++ ----------------
__global__ void k_degree(const int* __restrict__ ei, int* __restrict__ deg) {
    int e = blockIdx.x * 256 + threadIdx.x;
    if (e < NE) atomicAdd(&deg[ei[NE + e]], 1);
}

// ---------------- scan stage 1: per-block sums ----------------
__global__ __launch_bounds__(256) void k_scan1(const int* __restrict__ deg, int* __restrict__ bsum) {
    __shared__ int red[64];
    int base = blockIdx.x * SCAN_BLK + threadIdx.x * 4;
    int s = 0;
    for (int j = 0; j < 4; j++) {
        int i = base + j;
        if (i < NN) s += deg[i];
    }
    for (int off = 32; off > 0; off >>= 1) s += __shfl_down(s, off, 64);
    int wave = threadIdx.x >> 6;
    if ((threadIdx.x & 63) == 0) red[wave] = s;
    __syncthreads();
    if (threadIdx.x == 0) bsum[blockIdx.x] = red[0] + red[1] + red[2] + red[3];
}

// ---------------- scan stage 2 ----------------
__global__ void k_scan2(int* __restrict__ bsum, int* __restrict__ row_start) {
    if (threadIdx.x == 0) {
        int run = 0;
        for (int b = 0; b < NB; b++) { int t = bsum[b]; bsum[b] = run; run += t; }
        row_start[NN] = NE;
    }
}

// ---------------- scan stage 3 (fills row_start and cursor) ----------------
__global__ __launch_bounds__(256) void k_scan3(const int* __restrict__ deg, const int* __restrict__ bsum,
                                               int* __restrict__ row_start, int* __restrict__ cursor) {
    __shared__ int s[256];
    int base = blockIdx.x * SCAN_BLK + threadIdx.x * 4;
    int v[4];
    int tot = 0;
    for (int j = 0; j < 4; j++) {
        int i = base + j;
        v[j] = (i < NN) ? deg[i] : 0;
        tot += v[j];
    }
    s[threadIdx.x] = tot;
    __syncthreads();
    for (int off = 1; off < 256; off <<= 1) {
        int x = (threadIdx.x >= off) ? s[threadIdx.x - off] : 0;
        __syncthreads();
        s[threadIdx.x] += x;
        __syncthreads();
    }
    int excl = s[threadIdx.x] - tot + bsum[blockIdx.x];
    for (int j = 0; j < 4; j++) {
        int i = base + j;
        if (i < NN) { row_start[i] = excl; cursor[i] = excl; excl += v[j]; }
    }
}

// ---------------- fill CSR: csr[pos] = {src, packed bf16 attrs} ----------------
__global__ void k_fill(const int* __restrict__ ei, const float* __restrict__ ea,
                       int* __restrict__ cursor, int2* __restrict__ csr) {
    int e = blockIdx.x * 256 + threadIdx.x;
    if (e >= NE) return;
    int src = ei[e];
    int dst = ei[NE + e];
    float2 a = *(const float2*)(ea + e * 2);
    int pos = atomicAdd(&cursor[dst], 1);
    int2 v;
    v.x = src;
    v.y = (int)(f2bf(a.x) | (f2bf(a.y) << 16));
    csr[pos] = v;
}

// ---------------- graph boundaries from sorted batch ----------------
__global__ void k_gstart(const int* __restrict__ batch, int* __restrict__ gstart) {
    int i = blockIdx.x * 256 + threadIdx.x;
    if (i >= NN) return;
    int b = batch[i];
    int p = (i == 0) ? -1 : batch[i - 1];
    for (int g = p + 1; g <= b; g++) gstart[g] = i;
    if (i == NN - 1) {
        for (int g = b + 1; g <= NG; g++) gstart[g] = NN;
    }
}

// ---------------- h0 = x @ in_w + in_b (bf16 out) ----------------
__global__ void k_init_h(const float* __restrict__ x, const float* __restrict__ w,
                         const float* __restrict__ b, ushort* __restrict__ h) {
    int t = blockIdx.x * 256 + threadIdx.x;
    int node = t >> 4;
    if (node >= NN) return;
    int c4 = (t & 15) * 4;
    float4 acc = *(const float4*)(b + c4);
    const float* xr = x + node * IN_DIM;
    for (int k = 0; k < IN_DIM; k++) {
        float xv = xr[k];
        float4 wv = *(const float4*)(w + k * H + c4);
        acc.x += xv * wv.x; acc.y += xv * wv.y;
        acc.z += xv * wv.z; acc.w += xv * wv.w;
    }
    uint2 o;
    o.x = f2bf(acc.x) | (f2bf(acc.y) << 16);
    o.y = f2bf(acc.z) | (f2bf(acc.w) << 16);
    *(uint2*)(h + (size_t)node * H + c4) = o;
}

// ---------------- fused GINE layer: gather + MLP + BN + relu ----------------
// 1024-thread blocks, 16 waves, ONE NODE PER WAVE (r8 structure). Test: if
// occupancy was capped by workgroup dispatch rate (r8: 4.8 blocks resident
// = launch rate x 6.6us lifetime, matching 59% occ), 4x bigger blocks ->
// ~32 waves/CU. If per-CU miss budget is the cap, no change (=roofline).
// No __syncthreads (wave-private LDS rows). VGPR<=64 via (1024,8): no spill
// (r4-r6 anomaly was spill at VGPR<=32).
__global__ __launch_bounds__(1024, 8) void k_conv(
    const ushort* __restrict__ h_in, ushort* __restrict__ h_out,
    const int2* __restrict__ csr, const int* __restrict__ row_start,
    const float* __restrict__ ew, const float* __restrict__ eb,
    const float* __restrict__ W1, const float* __restrict__ b1,
    const float* __restrict__ W2, const float* __restrict__ b2,
    const float* __restrict__ bnw, const float* __restrict__ bnb,
    const float* __restrict__ bnm, const float* __restrict__ bnv) {
    __shared__ float zs[CONV_W][H];
    __shared__ float ts[CONV_W][H];
    int w = threadIdx.x >> 6;
    int c = threadIdx.x & 63;
    int node = blockIdx.x * CONV_W + w;
    float ew0 = ew[c], ew1 = ew[H + c], ebc = eb[c];
    int rs = __builtin_amdgcn_readfirstlane(row_start[node]);
    int re = __builtin_amdgcn_readfirstlane(row_start[node + 1]);
    float acc = 0.f;
    int j = rs;
    for (; j + 16 <= re; j += 16) {
        int2 v[16];
        #pragma unroll
        for (int t = 0; t < 16; t++) v[t] = csr[j + t];
        float hh[16];
        #pragma unroll
        for (int t = 0; t < 16; t++) hh[t] = bf2f(h_in[(size_t)v[t].x * H + c]);
        #pragma unroll
        for (int t = 0; t < 16; t++)
            acc += fmaxf(hh[t] + fmaf(bf2f(v[t].y), ew0, fmaf(bf2f((uint)v[t].y >> 16), ew1, ebc)), 0.f);
    }
    for (; j + 4 <= re; j += 4) {
        int2 v[4];
        #pragma unroll
        for (int t = 0; t < 4; t++) v[t] = csr[j + t];
        float hh[4];
        #pragma unroll
        for (int t = 0; t < 4; t++) hh[t] = bf2f(h_in[(size_t)v[t].x * H + c]);
        #pragma unroll
        for (int t = 0; t < 4; t++)
            acc += fmaxf(hh[t] + fmaf(bf2f(v[t].y), ew0, fmaf(bf2f((uint)v[t].y >> 16), ew1, ebc)), 0.f);
    }
    for (; j < re; j++) {
        int2 v = csr[j];
        float hs = bf2f(h_in[(size_t)v.x * H + c]);
        acc += fmaxf(hs + fmaf(bf2f(v.y), ew0, fmaf(bf2f((uint)v.y >> 16), ew1, ebc)), 0.f);
    }
    float z = bf2f(h_in[(size_t)node * H + c]) + acc;
    zs[w][c] = z;
    float a1 = b1[c];
    for (int k = 0; k < H; k += 4) {
        float4 zv = *(const float4*)&zs[w][k];
        a1 = fmaf(zv.x, W1[(k + 0) * H + c], a1);
        a1 = fmaf(zv.y, W1[(k + 1) * H + c], a1);
        a1 = fmaf(zv.z, W1[(k + 2) * H + c], a1);
        a1 = fmaf(zv.w, W1[(k + 3) * H + c], a1);
    }
    ts[w][c] = fmaxf(a1, 0.f);
    float a2 = b2[c];
    for (int k = 0; k < H; k += 4) {
        float4 tv = *(const float4*)&ts[w][k];
        a2 = fmaf(tv.x, W2[(k + 0) * H + c], a2);
        a2 = fmaf(tv.y, W2[(k + 1) * H + c], a2);
        a2 = fmaf(tv.z, W2[(k + 2) * H + c], a2);
        a2 = fmaf(tv.w, W2[(k + 3) * H + c], a2);
    }
    float scale = bnw[c] * rsqrtf(bnv[c] + BN_EPS);
    float hn = fmaxf((a2 - bnm[c]) * scale + bnb[c], 0.f);
    // pack 2 channels -> 1 dword store by even lanes
    uint me = f2bf(hn);
    uint nb = __shfl_down(me, 1, 64);
    if ((c & 1) == 0) {
        *(uint*)(h_out + (size_t)node * H + c) = me | (nb << 16);
    }
}

// ---------------- fused pooling + vn MLP + h += vn (addvn fused) ----------
// one wave per graph; batch sorted so graph = contiguous node range.
__global__ __launch_bounds__(256) void k_poolvn(ushort* __restrict__ h,
                                                const int* __restrict__ gstart,
                                                float* __restrict__ pooled,
                                                const float* __restrict__ w1, const float* __restrict__ b1,
                                                const float* __restrict__ w2, const float* __restrict__ b2,
                                                float* __restrict__ vn, int do_vn) {
    __shared__ float ps[4][H];
    __shared__ float ts[4][H];
    int w = threadIdx.x >> 6, c = threadIdx.x & 63;
    int g = blockIdx.x * 4 + w;
    int s = __builtin_amdgcn_readfirstlane(gstart[g]);
    int e = __builtin_amdgcn_readfirstlane(gstart[g + 1]);
    float acc = 0.f;
    int n = s;
    for (; n + 4 <= e; n += 4) {
        float x0 = bf2f(h[(size_t)(n + 0) * H + c]);
        float x1 = bf2f(h[(size_t)(n + 1) * H + c]);
        float x2 = bf2f(h[(size_t)(n + 2) * H + c]);
        float x3 = bf2f(h[(size_t)(n + 3) * H + c]);
        acc += x0; acc += x1; acc += x2; acc += x3;
    }
    for (; n < e; n++) acc += bf2f(h[(size_t)n * H + c]);
    pooled[(size_t)g * H + c] = acc;
    if (!do_vn) return;
    ps[w][c] = acc;
    float a1 = b1[c];
    for (int k = 0; k < H; k += 4) {
        float4 pv = *(const float4*)&ps[w][k];
        a1 = fmaf(pv.x, w1[(k + 0) * H + c], a1);
        a1 = fmaf(pv.y, w1[(k + 1) * H + c], a1);
        a1 = fmaf(pv.z, w1[(k + 2) * H + c], a1);
        a1 = fmaf(pv.w, w1[(k + 3) * H + c], a1);
    }
    ts[w][c] = fmaxf(a1, 0.f);
    float a2 = b2[c];
    for (int k = 0; k < H; k += 4) {
        float4 tv = *(const float4*)&ts[w][k];
        a2 = fmaf(tv.x, w2[(k + 0) * H + c], a2);
        a2 = fmaf(tv.y, w2[(k + 1) * H + c], a2);
        a2 = fmaf(tv.z, w2[(k + 2) * H + c], a2);
        a2 = fmaf(tv.w, w2[(k + 3) * H + c], a2);
    }
    float vnew = vn[(size_t)g * H + c] + a2;
    vn[(size_t)g * H + c] = vnew;
    // ---- fused addvn: h[n] += vnew for all nodes n of graph g ----
    ps[w][c] = vnew;
    float vlo = ps[w][(c & 31) * 2 + 0];
    float vhi = ps[w][(c & 31) * 2 + 1];
    int ch2 = (c & 31) * 2;
    for (n = s; n + 2 <= e; n += 2) {
        size_t off = (size_t)(n + (c >> 5)) * H + ch2;
        uint u = *(uint*)(h + off);
        float lo = bf2f(u) + vlo;
        float hi = bf2f(u >> 16) + vhi;
        *(uint*)(h + off) = f2bf(lo) | (f2bf(hi) << 16);
    }
    if (n < e && c < 32) {   // odd tail
        size_t off = (size_t)n * H + ch2;
        uint u = *(uint*)(h + off);
        float lo = bf2f(u) + vlo;
        float hi = bf2f(u >> 16) + vhi;
        *(uint*)(h + off) = f2bf(lo) | (f2bf(hi) << 16);
    }
}

// ---------------- final: mean pool, pep MLP, classifier ----------------
__global__ __launch_bounds__(256) void k_final(const float* __restrict__ pooled,
                                               const int* __restrict__ gstart,
                                               const float* __restrict__ pep,
                                               const float* __restrict__ pw, const float* __restrict__ pb,
                                               const float* __restrict__ cw1, const float* __restrict__ cb1,
                                               const float* __restrict__ cw2, const float* __restrict__ cb2,
                                               float* __restrict__ out) {
    __shared__ float red[4][H];
    __shared__ float fused[2 * H];
    int g = blockIdx.x;
    int lane = threadIdx.x & 63;
    int part = threadIdx.x >> 6;
    const float* pr = pep + (size_t)g * PEP_DIM;
    float acc = 0.0f;
    int k0 = part * (PEP_DIM / 4);
    for (int k = k0; k < k0 + PEP_DIM / 4; k++) {
        acc += pr[k] * pw[k * H + lane];
    }
    red[part][lane] = acc;
    __syncthreads();
    if (part == 0) {
        float s = red[0][lane] + red[1][lane] + red[2][lane] + red[3][lane] + pb[lane];
        fused[H + lane] = fmaxf(s, 0.0f);
        float c = (float)(gstart[g + 1] - gstart[g]);
        float invc = 1.0f / fmaxf(c, 1.0f);
        fused[lane] = pooled[(size_t)g * H + lane] * invc;
    }
    __syncthreads();
    if (part == 0) {
        float a = cb1[lane];
        for (int k = 0; k < 2 * H; k++) a += fused[k] * cw1[k * H + lane];
        float t = fmaxf(a, 0.0f);
        float v = t * cw2[lane];
        for (int off = 32; off > 0; off >>= 1) v += __shfl_down(v, off, 64);
        if (lane == 0) out[g] = v + cb2[0];
    }
}

extern "C" void kernel_launch(void* const* d_in, const int* in_sizes, int n_in,
                              void* d_out, int out_size, void* d_ws, size_t ws_size,
                              hipStream_t stream) {
    const float* x        = (const float*)d_in[0];
    const int*   ei       = (const int*)d_in[1];
    const int*   batch    = (const int*)d_in[2];
    const float* ea       = (const float*)d_in[3];
    const float* pep      = (const float*)d_in[4];
    const float* in_w     = (const float*)d_in[5];
    const float* in_b     = (const float*)d_in[6];
    const float* e_w      = (const float*)d_in[7];
    const float* e_b      = (const float*)d_in[8];
    const float* conv_w1  = (const float*)d_in[9];
    const float* conv_b1  = (const float*)d_in[10];
    const float* conv_w2  = (const float*)d_in[11];
    const float* conv_b2  = (const float*)d_in[12];
    const float* bn_w     = (const float*)d_in[13];
    const float* bn_b     = (const float*)d_in[14];
    const float* bn_mean  = (const float*)d_in[15];
    const float* bn_var   = (const float*)d_in[16];
    const float* vn_w1    = (const float*)d_in[17];
    const float* vn_b1    = (const float*)d_in[18];
    const float* vn_w2    = (const float*)d_in[19];
    const float* vn_b2    = (const float*)d_in[20];
    const float* pep_w    = (const float*)d_in[21];
    const float* pep_b    = (const float*)d_in[22];
    const float* cls_w1   = (const float*)d_in[23];
    const float* cls_b1   = (const float*)d_in[24];
    const float* cls_w2   = (const float*)d_in[25];
    const float* cls_b2   = (const float*)d_in[26];
    float* out = (float*)d_out;

    // ---- workspace layout ----
    ushort* h_a   = (ushort*)d_ws;                    // NN*H bf16
    ushort* h_b   = h_a + (size_t)NN * H;             // NN*H bf16
    float* pooled = (float*)(h_b + (size_t)NN * H);   // NG*H
    float* vn     = pooled + (size_t)NG * H;          // NG*H
    int2*  csr    = (int2*)(vn + (size_t)NG * H);     // NE (8B each)
    int* row_start = (int*)(csr + (size_t)NE);        // NN+16
    int* cursor    = row_start + NN + 16;             // NN+16
    int* gstart    = cursor + NN + 16;                // NG+16
    int* bsum      = gstart + NG + 16;                // NB (<=128)

    // ---- build CSR (once; reused by all 3 layers) ----
    hipMemsetAsync(cursor, 0, (size_t)NN * sizeof(int), stream);
    k_degree<<<(NE + 255) / 256, 256, 0, stream>>>(ei, cursor);
    k_scan1<<<NB, 256, 0, stream>>>(cursor, bsum);
    k_scan2<<<1, 64, 0, stream>>>(bsum, row_start);
    k_scan3<<<NB, 256, 0, stream>>>(cursor, bsum, row_start, cursor);
    k_fill<<<(NE + 255) / 256, 256, 0, stream>>>(ei, ea, cursor, csr);
    k_gstart<<<(NN + 255) / 256, 256, 0, stream>>>(batch, gstart);

    // ---- init ----
    k_init_h<<<NN * 16 / 256, 256, 0, stream>>>(x, in_w, in_b, h_a);
    hipMemsetAsync(vn, 0, (size_t)NG * H * sizeof(float), stream);

    ushort* hc = h_a;
    ushort* hn = h_b;
    for (int i = 0; i < 3; i++) {
        k_conv<<<NN / CONV_W, 1024, 0, stream>>>(hc, hn, csr, row_start,
                                           e_w, e_b,
                                           conv_w1 + i * H * H, conv_b1 + i * H,
                                           conv_w2 + i * H * H, conv_b2 + i * H,
                                           bn_w + i * H, bn_b + i * H,
                                           bn_mean + i * H, bn_var + i * H);
        ushort* t = hc; hc = hn; hn = t;   // hc now holds layer output
        k_poolvn<<<NG / 4, 256, 0, stream>>>(hc, gstart, pooled,
                                             vn_w1, vn_b1, vn_w2, vn_b2, vn,
                                             (i < 2) ? 1 : 0);
    }

    k_final<<<NG, 256, 0, stream>>>(pooled, gstart, pep, pep_w, pep_b,
                                    cls_w1, cls_b1, cls_w2, cls_b2, out);
}